// Round 1
// baseline (150.395 us; speedup 1.0000x reference)
//
#include <hip/hip_runtime.h>
#include <hip/hip_fp16.h>
#include <stdint.h>

// OrthogonalLinear: pyramid Givens circuit, n = m = 512, B = 256, T = 1021 layers.
// Layer t has gates (i, i+1) for i = (t&1), (t&1)+2, ..., i <= min(t, 1020-t).
// theta index for gate (t, i): k = (t+i)/2 + 1, idx = k(k-1)/2 + (k-1-i).
//
// R11: 4-wave row split. Block = 256 threads = one row. Thread u (0..255) owns
// wire pair (2u, 2u+1) in registers (E, O). Layer pair p = layers (2p, 2p+1):
//   even layer: gate (2u, 2u+1) is lane-local.
//   odd layer:  gate (2u+1, 2u+2): O-side needs E(u+1), E-side needs O(u-1) --
//               wave_shl1/shr1 DPP inside a wave; 1-float LDS ping-pong +
//               one raw s_barrier per pair at the 3 wave seams (no vmcnt drain,
//               so the PF=8 global prefetch ring stays in flight across barriers).
// Gate table: one uint4 per (pair, u), all f16 half2, consumed directly by
// v_fma_mix_f32 (zero cvt instructions, zero neg modifiers):
//   .x ge   = (c_e,  s_e)   even gate (2u,2u+1)
//   .y ge2  = (c_e, -s_e)   sign-folded copy for the O side
//   .z god  = (c_o,  s_o)   odd gate (2u+1,2u+2)  (a-side, own O)
//   .w godm = (c_o', -s_o') odd gate (2u-1,2u) params, pre-shifted + sign-folded
// Pair 510 = final even layer t=1020 (odd half identity). Pair 511 = identity
// pad so the ring can overrun. Table = 512*256*16B = 2.10 MB in d_ws.

#define BATCH 256
#define PF 8          // prefetch ring depth; main loop 63*8 = 504, drain 7

static __device__ __forceinline__ uint32_t pack_cs(float c, float s) {
  __half2 h = __floats2half2_rn(c, s);   // lo = c, hi = s
  return __builtin_bit_cast(uint32_t, h);
}

// ---------------- kernel 1: f16 gate-record table build ----------------
__global__ __launch_bounds__(256) void fused_kernel(
    const float* __restrict__ thetas, uint4* __restrict__ W) {
  const int p = blockIdx.x;    // layer pair 0..511 (511 = identity pad)
  const int u = threadIdx.x;   // wire-pair index 0..255
  float ce = 1.f, se = 0.f, co = 1.f, so = 0.f;
  const int lime = min(p, 510 - p);        // even gate i=2u valid iff u <= lime
  if (u <= lime) {
    int a = p + u;                         // k-1 = p+u
    __sincosf(thetas[((a + 1) * a) / 2 + (p - u)], &se, &ce);
  }
  const int limo = min(p, 509 - p);        // odd gate i=2u+1 valid iff u <= limo
  if (u <= limo) {
    int a = p + u + 1;                     // k-1 = p+u+1
    __sincosf(thetas[((a + 1) * a) / 2 + (p - u)], &so, &co);
  }
  uint32_t ge  = pack_cs(ce, se);
  uint32_t god = pack_cs(co, so);
  // godm = god(u-1): wave shift; first lane of each wave recomputes directly.
  uint32_t godm = (uint32_t)__builtin_amdgcn_mov_dpp((int)god, 0x138, 0xF, 0xF, true);
  if ((u & 63) == 0) {
    float cm = 1.f, sm = 0.f;
    if (u > 0 && (u - 1) <= limo) {
      int a = p + u;                       // = p + (u-1) + 1
      __sincosf(thetas[((a + 1) * a) / 2 + (p - (u - 1))], &sm, &cm);
    }
    godm = pack_cs(cm, sm);
  }
  W[p * 256 + u] = make_uint4(ge, ge ^ 0x80000000u, god, godm ^ 0x80000000u);
}

// ---------------- kernel 2: circuit, 4 waves per row ----------------
template <int N>
__device__ __forceinline__ void wait_vm() {
  asm volatile("s_waitcnt vmcnt(%0)" ::"i"(N) : "memory");
}
__device__ __forceinline__ void lds_barrier() {
  // raw barrier: waits LDS only -- the global prefetch ring stays outstanding
  asm volatile("s_waitcnt lgkmcnt(0)\n\ts_barrier" ::: "memory");
}
__device__ __forceinline__ float dpp_shr1(float v) {  // lane i <- i-1; lane0 <- 0
  return __int_as_float(
      __builtin_amdgcn_mov_dpp(__float_as_int(v), 0x138, 0xF, 0xF, true));
}
__device__ __forceinline__ float dpp_shl1(float v) {  // lane i <- i+1; lane63 <- 0
  return __int_as_float(
      __builtin_amdgcn_mov_dpp(__float_as_int(v), 0x130, 0xF, 0xF, true));
}
// f16(hi of g) * b          (one VOP3P, no convert)
__device__ __forceinline__ float mix_hi(uint32_t g, float b) {
  float d;
  asm("v_fma_mix_f32 %0, %1, %2, 0 op_sel:[1,0,0] op_sel_hi:[1,0,0]"
      : "=v"(d)
      : "v"(g), "v"(b));
  return d;
}
// f16(lo of g) * b + acc
__device__ __forceinline__ float mix_lo_acc(uint32_t g, float b, float acc) {
  float d;
  asm("v_fma_mix_f32 %0, %1, %2, %3 op_sel:[0,0,0] op_sel_hi:[1,0,0]"
      : "=v"(d)
      : "v"(g), "v"(b), "v"(acc));
  return d;
}

__device__ __forceinline__ void pair_body(float& E, float& O, const uint4 r,
                                          float* __restrict__ xch, int wi,
                                          int ri, bool l0, bool l63) {
  // even layer, gate (2u, 2u+1):  nE = c*E + s*O ; nO = c*O - s*E
  float t0 = mix_hi(r.x, O);
  float nE = mix_lo_acc(r.x, E, t0);
  float t1 = mix_hi(r.y, E);            // (-s)*E via sign-folded ge2
  float nO = mix_lo_acc(r.y, O, t1);
  // seam exchange of post-even edge values (1 float per seam, per direction)
  xch[wi] = l63 ? nO : nE;
  lds_barrier();
  float lv = xch[ri];
  float En = dpp_shl1(nE);              // E(u+1) for interior lanes
  float Op = dpp_shr1(nO);              // O(u-1) for interior lanes
  En = l63 ? lv : En;
  Op = l0 ? lv : Op;
  // odd layer: own-O is a-side of (2u+1,2u+2); own-E is b-side of (2u-1,2u)
  float t2 = mix_hi(r.z, En);           //  so*En
  O = mix_lo_acc(r.z, nO, t2);          //  co*nO + so*En
  float t3 = mix_hi(r.w, Op);           // -so'*Op via sign-folded godm
  E = mix_lo_acc(r.w, nE, t3);          //  co'*nE - so'*Op
}

__global__ __launch_bounds__(256, 1) void circuit_kernel(
    const float* __restrict__ x, const uint4* __restrict__ W,
    const float* __restrict__ bias, float* __restrict__ out) {
  const int tid = threadIdx.x;       // u = wire-pair index
  const int lane = tid & 63;
  const int w = tid >> 6;            // wave 0..3
  const int row = blockIdx.x;

  // LDS: per parity 16 floats: [0..4] eX slots (4 = guard), [8..12] oX slots
  // (8 = guard). [32..287] trash (per-thread dump for unpredicated ds ops).
  __shared__ float xch[288];

  const bool l0 = (lane == 0), l63 = (lane == 63);

  // per-parity write/read indices (compile-time selected in the unrolled loop)
  int wi[2], ri[2];
#pragma unroll
  for (int par = 0; par < 2; ++par) {
    int base = par * 16;
    int wv = 32 + tid, rv = 32 + tid;
    if (l0)  { wv = base + w;         rv = base + 8 + w; }
    if (l63) { wv = base + 8 + w + 1; rv = base + w + 1; }
    wi[par] = wv; ri[par] = rv;
  }
  if (tid == 0) { xch[4] = 0.f; xch[8] = 0.f; xch[20] = 0.f; xch[24] = 0.f; }

  const float2 xv = *reinterpret_cast<const float2*>(x + row * 512 + 2 * tid);
  asm volatile("s_waitcnt vmcnt(0)" ::: "memory");  // x done; orders ring loads after
  float E = xv.x, O = xv.y;
  lds_barrier();  // guard slots visible to all waves

  uint4 R[PF];
  const uint4* __restrict__ Wr = W + tid;
#pragma unroll
  for (int s = 0; s < PF; ++s) R[s] = Wr[s * 256];

  int base = PF * 256;
  for (int blk = 0; blk < 63; ++blk) {   // pairs 0..503
#pragma unroll
    for (int s = 0; s < PF; ++s) {
      wait_vm<PF - 1>();                 // oldest ring load (this pair) done
      const uint4 r = R[s];
      R[s] = Wr[base + s * 256];         // prefetch pair g+8 (<= 511 pad)
      pair_body(E, O, r, xch, wi[s & 1], ri[s & 1], l0, l63);
    }
    base += PF * 256;
  }
  wait_vm<0>();
#pragma unroll
  for (int s = 0; s < 7; ++s) {          // pairs 504..510 (incl. final t=1020)
    pair_body(E, O, R[s], xch, wi[s & 1], ri[s & 1], l0, l63);
  }

  const float2 bv = *reinterpret_cast<const float2*>(bias + 2 * tid);
  float2 ov;
  ov.x = E + bv.x;
  ov.y = O + bv.y;
  *reinterpret_cast<float2*>(out + row * 512 + 2 * tid) = ov;
}

extern "C" void kernel_launch(void* const* d_in, const int* in_sizes, int n_in,
                              void* d_out, int out_size, void* d_ws,
                              size_t ws_size, hipStream_t stream) {
  const float* x = (const float*)d_in[0];       // (256, 512) f32
  const float* thetas = (const float*)d_in[1];  // (130816,) f32
  const float* bias = (const float*)d_in[2];    // (512,) f32
  float* out = (float*)d_out;                   // (256, 512) f32

  uint4* W = (uint4*)d_ws;  // 512 pairs * 256 records * 16 B = 2,097,152 B

  fused_kernel<<<512, 256, 0, stream>>>(thetas, W);
  circuit_kernel<<<BATCH, 256, 0, stream>>>(x, W, bias, out);
}

// Round 2
// 115.535 us; speedup vs baseline: 1.3017x; 1.3017x over previous
//
#include <hip/hip_runtime.h>
#include <hip/hip_fp16.h>
#include <stdint.h>

// OrthogonalLinear: pyramid Givens circuit, n = m = 512, B = 256.
// T = 1021 layers; layer t has gates (i, i+1) for i = (t&1), (t&1)+2, ...,
// i <= min(t, 1020-t). theta index: k = (t+i)/2 + 1, idx = k(k-1)/2 + (k-1-i).
//
// R12 = R10's proven wave-per-row structure (register ring PF=10, DPP seams,
// f16 half2(c,s) table, boundary gate stored as (c-1, s) so the DPP-shifted-in
// zero dword decodes to identity) with the ENTIRE gate math rewritten as
// v_fma_mix_f32 consuming the f16 table directly: zero v_cvt, zero v_pk
// (half-rate VOP3P), ~42 full-rate VALU slots/pair vs ~60 before.
// R11 validated mix-op numerics (passed, absmax 0.03125); R11's 4-wave
// per-pair barrier structure is abandoned (442 cyc/pair, seam-dominated).
//
// Table layout (R10, unchanged): pair p (layers t=2p, 2p+1) = 128 uint4:
// uint4 idx = p*128 + h*64 + L; h=0 -> even-layer gates of lane L at wires
// 8L+{0,2,4,6}; h=1 -> odd-layer gates at wires 8L+{1,3,5}, .w = boundary
// gate (8L+7, 8L+8) as half2(c-1, s). Final even layer t=1020 at
// [FINAL4, FINAL4+64), plain (c,s). Dead slots = identity.

#define N_WIRES 512
#define BATCH   256
#define PAIRS   510
#define PF      10                  // ring depth; 510 = 10 * 51
#define FINAL4  (PAIRS * 128)       // 65280 uint4
#define TOTAL4  (FINAL4 + 64)       // 65344 uint4
#define TOTALH2 (TOTAL4 * 4)        // 261376 half2 slots

// ---------------- kernel 1: fused f16 table build (R10, unchanged) --------
__global__ __launch_bounds__(256) void fused_kernel(
    const float* __restrict__ thetas, __half2* __restrict__ Wh) {
  int tid = blockIdx.x * 256 + threadIdx.x;
  if (tid >= TOTALH2) return;
  float c = 1.0f, s = 0.0f;
  if (tid < PAIRS * 512) {
    int p = tid >> 9, r = tid & 511;
    int h = r >> 8, rr = r & 255, L = rr >> 2, j = rr & 3;
    int t = 2 * p + h;
    int i = 8 * L + 2 * j + h;
    if (i <= min(t, 1020 - t)) {
      int k = ((t + i) >> 1) + 1;
      int idx = ((k * (k - 1)) >> 1) + (k - 1 - i);
      __sincosf(thetas[idx], &s, &c);
    }
    if (h == 1 && j == 3) c -= 1.0f;   // boundary gate stored as (c-1, s)
  } else {
    int e = tid - PAIRS * 512;         // final even layer t = 1020
    int L = e >> 2, j = e & 3;
    if (8 * L + 2 * j == 0) __sincosf(thetas[130815], &s, &c);
  }
  Wh[tid] = __floats2half2_rn(c, s);
}

// ---------------- kernel 2: apply circuit, wave per row -------------------
template <int N>
__device__ __forceinline__ void wait_vm() {
  asm volatile("s_waitcnt vmcnt(%0)" ::"i"(N) : "memory");
}

__device__ __forceinline__ float dpp_shr1(float v) {  // lane i <- i-1; lane0 <- 0
  return __int_as_float(
      __builtin_amdgcn_mov_dpp(__float_as_int(v), 0x138, 0xF, 0xF, true));
}
__device__ __forceinline__ float dpp_shl1(float v) {  // lane i <- i+1; lane63 <- 0
  return __int_as_float(
      __builtin_amdgcn_mov_dpp(__float_as_int(v), 0x130, 0xF, 0xF, true));
}
__device__ __forceinline__ uint32_t dpp_shr1_u(uint32_t v) {
  return (uint32_t)__builtin_amdgcn_mov_dpp((int)v, 0x138, 0xF, 0xF, true);
}

// d = f16hi(g) * b          (s * b)   -- one full-rate VOP3P, no convert
__device__ __forceinline__ float mix_s(uint32_t g, float b) {
  float d;
  asm("v_fma_mix_f32 %0, %1, %2, 0 op_sel:[1,0,0] op_sel_hi:[1,0,0]"
      : "=v"(d)
      : "v"(g), "v"(b));
  return d;
}
// d = -f16hi(g) * b         (-s * b)
__device__ __forceinline__ float mix_ns(uint32_t g, float b) {
  float d;
  asm("v_fma_mix_f32 %0, -%1, %2, 0 op_sel:[1,0,0] op_sel_hi:[1,0,0]"
      : "=v"(d)
      : "v"(g), "v"(b));
  return d;
}
// d = f16lo(g) * b + acc    (c * b + acc)
__device__ __forceinline__ float mix_c_acc(uint32_t g, float b, float acc) {
  float d;
  asm("v_fma_mix_f32 %0, %1, %2, %3 op_sel:[0,0,0] op_sel_hi:[1,0,0]"
      : "=v"(d)
      : "v"(g), "v"(b), "v"(acc));
  return d;
}

// Full interior Givens gate on (a, b) with g = half2(c, s):
//   a' = c*a + s*b ; b' = c*b - s*a.  4 full-rate mix ops, depth 2.
__device__ __forceinline__ void gate_mix(float& a, float& b, uint32_t g) {
  float t = mix_s(g, b);            //  s*b
  float u = mix_ns(g, a);           // -s*a
  float na = mix_c_acc(g, a, t);    //  c*a + s*b
  float nb = mix_c_acc(g, b, u);    //  c*b - s*a
  a = na;
  b = nb;
}

__device__ __forceinline__ void pair_compute(float& v0, float& v1, float& v2,
                                             float& v3, float& v4, float& v5,
                                             float& v6, float& v7,
                                             const uint4& E, const uint4& O) {
  // even layer: gates (8L+0,1) (8L+2,3) (8L+4,5) (8L+6,7)
  gate_mix(v0, v1, E.x);
  gate_mix(v2, v3, E.y);
  gate_mix(v4, v5, E.z);
  gate_mix(v6, v7, E.w);
  // cross-lane halo on post-even values (boundary gate dword moves as a unit;
  // lane0's shifted-in 0 decodes to identity since table stores (c-1, s))
  uint32_t bl = dpp_shr1_u(O.w);    // left neighbor's boundary gate (8L-1, 8L)
  float rv0 = dpp_shl1(v0);         // right neighbor's wire 8L+8 (post-even)
  float lv7 = dpp_shr1(v7);         // left neighbor's wire 8L-1 (post-even)
  // odd layer interior: gates (8L+1,2) (8L+3,4) (8L+5,6)
  gate_mix(v1, v2, O.x);
  gate_mix(v3, v4, O.y);
  gate_mix(v5, v6, O.z);
  // up-gate (8L+7, 8L+8) a-side, c = 1 + c':  v7' = s*rv0 + c'*v7 + v7
  float t = mix_s(O.w, rv0);
  t = mix_c_acc(O.w, v7, t);
  v7 = t + v7;
  // down-gate (8L-1, 8L) b-side, c = 1 + c':  v0' = -s*lv7 + c'*v0 + v0
  float u = mix_ns(bl, lv7);
  u = mix_c_acc(bl, v0, u);
  v0 = u + v0;
}

__global__ __launch_bounds__(64, 1) void circuit_kernel(
    const float* __restrict__ x, const uint32_t* __restrict__ W,
    const float* __restrict__ bias, float* __restrict__ out) {
  const int lane = threadIdx.x;
  const int row = blockIdx.x;
  const uint4* __restrict__ Wg = (const uint4*)W;

  // Register ring: PF pairs x 2 uint4 = 80 VGPRs. Pointer induction.
  uint4 R[PF][2];
  const uint4* pw = Wg + lane;
#pragma unroll
  for (int s = 0; s < PF; ++s) {
    R[s][0] = pw[0];     // even-layer quad
    R[s][1] = pw[64];    // odd-layer quad
    pw += 128;
  }

  const float* xr = x + row * N_WIRES + lane * 8;
  float4 x0 = *(const float4*)(xr);
  float4 x1 = *(const float4*)(xr + 4);
  float v0 = x0.x, v1 = x0.y, v2 = x0.z, v3 = x0.w;
  float v4 = x1.x, v5 = x1.y, v6 = x1.z, v7 = x1.w;

  for (int blk = 0; blk < (PAIRS / PF) - 1; ++blk) {   // 50 iterations
#pragma unroll
    for (int s = 0; s < PF; ++s) {
      // outstanding = 20 table loads; retire exactly the oldest pair's 2.
      wait_vm<18>();
      pair_compute(v0, v1, v2, v3, v4, v5, v6, v7, R[s][0], R[s][1]);
      R[s][0] = pw[0];
      R[s][1] = pw[64];
      pw += 128;
    }
  }

  // Drain: pairs 500..509 already in ring; one full wait.
  wait_vm<0>();
#pragma unroll
  for (int s = 0; s < PF; ++s)
    pair_compute(v0, v1, v2, v3, v4, v5, v6, v7, R[s][0], R[s][1]);

  // Final even layer t = 1020 (plain (c,s), pre-masked identity).
  uint4 F = Wg[FINAL4 + lane];
  gate_mix(v0, v1, F.x);
  gate_mix(v2, v3, F.y);
  gate_mix(v4, v5, F.z);
  gate_mix(v6, v7, F.w);

  const float* br = bias + lane * 8;
  float4 b0 = *(const float4*)(br);
  float4 b1 = *(const float4*)(br + 4);
  float* orow = out + row * N_WIRES + lane * 8;
  float4 o0 = {v0 + b0.x, v1 + b0.y, v2 + b0.z, v3 + b0.w};
  float4 o1 = {v4 + b1.x, v5 + b1.y, v6 + b1.z, v7 + b1.w};
  *(float4*)(orow) = o0;
  *(float4*)(orow + 4) = o1;
}

extern "C" void kernel_launch(void* const* d_in, const int* in_sizes, int n_in,
                              void* d_out, int out_size, void* d_ws,
                              size_t ws_size, hipStream_t stream) {
  const float* x = (const float*)d_in[0];       // (256, 512) f32
  const float* thetas = (const float*)d_in[1];  // (130816,) f32
  const float* bias = (const float*)d_in[2];    // (512,) f32
  float* out = (float*)d_out;                   // (256, 512) f32

  uint32_t* W = (uint32_t*)d_ws;                // 65344 uint4 = 1,045,504 B

  fused_kernel<<<(TOTALH2 + 255) / 256, 256, 0, stream>>>(thetas, (__half2*)W);
  circuit_kernel<<<BATCH, 64, 0, stream>>>(x, W, bias, out);
}